// Round 6
// baseline (1228.419 us; speedup 1.0000x reference)
//
#include <hip/hip_runtime.h>
#include <stdint.h>

#define BATCH 8
#define HEADS 8
#define HM 128
#define WM 128
#define NPIX (HM*WM)      // 16384
#define DIMC 128
#define DH 64
#define GS 64
#define INNER 512
#define KTOT 1152         // 9*128 folded conv K
#define XT_LD 128         // bf16 X row: NO pad; XOR swizzle supplies bank spread

typedef unsigned short u16;
typedef short v8s __attribute__((ext_vector_type(8)));   // 8 bf16 in 4 VGPRs
typedef float v4f __attribute__((ext_vector_type(4)));   // MFMA accum

__device__ __forceinline__ u16 f2bf(float f) {
    unsigned x = __float_as_uint(f);
    return (u16)((x + 0x7fffu + ((x >> 16) & 1u)) >> 16);   // RNE
}
__device__ __forceinline__ float bf2f(u16 u) { return __uint_as_float(((unsigned)u) << 16); }
__device__ __forceinline__ unsigned cvtpk(float lo, float hi) {   // HW RNE pack: {hi,lo}
    unsigned r;
    asm("v_cvt_pk_bf16_f32 %0, %1, %2" : "=v"(r) : "v"(lo), "v"(hi));
    return r;
}

union BF8 { uint4 v; u16 s[8]; };

// ---------------------------------------------------------------------------
// Build folded logit weights, TRANSPOSED + bf16 (unchanged, verified).
// ---------------------------------------------------------------------------
__global__ __launch_bounds__(256) void k_build_w(
    const float* __restrict__ wx, const float* __restrict__ wfx,
    const float* __restrict__ slw, const float* __restrict__ temp,
    u16* __restrict__ wcatT, u16* __restrict__ wfxT)
{
    __shared__ float sw_l[GS][DH + 1];
    __shared__ float wx_l[INNER];
    int row = blockIdx.x;            // 0..1151
    int t = threadIdx.x;
    for (int i = t; i < GS * DH; i += 256) sw_l[i >> 6][i & 63] = slw[i];
    for (int i = t; i < INNER; i += 256) wx_l[i] = wx[(size_t)row * INNER + i];
    __syncthreads();
#pragma unroll
    for (int j = 0; j < 2; j++) {
        int co = j * 256 + t;
        int h = co >> 6, g = co & 63;
        float s = 0.f;
        for (int c = 0; c < DH; c++) s = fmaf(wx_l[h * 64 + c], sw_l[g][c], s);
        float tv = fminf(fmaxf(temp[h], 0.1f), 5.0f);
        wcatT[(size_t)co * KTOT + row] = f2bf(s / tv);
        wfxT[(size_t)co * KTOT + row] = f2bf(wfx[(size_t)row * INNER + co]);
    }
}

__global__ __launch_bounds__(512) void k_build_b(
    const float* __restrict__ bx, const float* __restrict__ slw,
    const float* __restrict__ slb, const float* __restrict__ temp,
    float* __restrict__ bcatL)
{
    int co = threadIdx.x;            // 0..511
    int h = co >> 6, g = co & 63;
    float s = slb[g];
    for (int c = 0; c < DH; c++) s = fmaf(bx[h * 64 + c], slw[g * 64 + c], s);
    float tv = fminf(fmaxf(temp[h], 0.1f), 5.0f);
    bcatL[co] = s / tv;
}

// ---------------------------------------------------------------------------
// Fused conv kernel v5: 256 threads (4 waves), grid 8192 (XCD-swizzled).
//  Block = (b, y, px-half) x head-pair ct: 64 px x 128 co, BOTH convs.
//  Wave = (w_conv in {L,F}) x (w_co = head-in-pair): 64px x 64co x 1 conv
//  -> acc = 16 v4f (64 regs). __launch_bounds__(256,4): <=128 regs/wave ->
//  4 waves/SIMD -> 4 INDEPENDENT blocks/CU (latency hiding via TLP).
//  - X staged per ky: 66 halo rows, bf16 cvt_pk, XOR-swizzled (LD=128).
//  - B fragments: direct per-lane global loads (L2-resident weights),
//    compile-time offsets; no reg double-buffer (TLP hides L2 latency).
//  - Epilogue: verified softmax-in-regs (L waves); 2 single-head rounds of
//    scatter / pool-MFMA (K=64) / swbT store; SwT/FxT 16 KB.
// ---------------------------------------------------------------------------
union SmemC {
    u16 X[66 * XT_LD];                                      // 16,896 B
    struct { u16 SwT[64][64]; u16 FxT[64][64]; } e;         // 16,384 B
};

__global__ __launch_bounds__(256, 4) void k_conv2(
    const float* __restrict__ xin, const u16* __restrict__ wcatT,
    const u16* __restrict__ wfxT, const float* __restrict__ bcatL,
    const float* __restrict__ bfx, u16* __restrict__ swbT,
    float* __restrict__ straw, float* __restrict__ norm)
{
    __shared__ SmemC sm;
    // XCD-chunked swizzle: consecutive swz within an XCD share (b,y) rows
    int bid = blockIdx.x;
    int swz = (bid & 7) * 1024 + (bid >> 3);
    int b = swz >> 10;
    int r = swz & 1023;
    int y = r >> 3, half = (r >> 2) & 1, ct = r & 3;
    int cob = ct << 7;
    int t = threadIdx.x;
    int lane = t & 63, wave = t >> 6;
    int w_conv = wave >> 1, w_co = wave & 1;
    int l16 = lane & 15, lk = lane >> 4;

    v4f acc[4][4];
#pragma unroll
    for (int i = 0; i < 4; i++)
#pragma unroll
        for (int j = 0; j < 4; j++) acc[i][j] = v4f{0.f, 0.f, 0.f, 0.f};

    // lane-resolved B row base pointers (per nj), table chosen per wave
    const u16* wT = w_conv ? wfxT : wcatT;
    const u16* wrb[4];
#pragma unroll
    for (int nj = 0; nj < 4; nj++)
        wrb[nj] = wT + (size_t)(cob + w_co * 64 + nj * 16 + l16) * KTOT + lk * 8;

#pragma unroll
    for (int ky = 0; ky < 3; ky++) {
        int yy = y + ky - 1;
        bool yok = (unsigned)yy < (unsigned)HM;
        const float* xrow = xin + ((size_t)b * NPIX + (size_t)yy * WM) * DIMC;
        if (ky) __syncthreads();     // previous ky's fragment readers done
        // ---- stage X(ky): 66 halo rows x 16 slots of 16B ----
#pragma unroll
        for (int it = 0; it < 5; it++) {
            int i = t + it * 256;
            if (i < 1056) {
                int row = i >> 4, k8 = i & 15;
                int px = half * 64 + row - 1;
                uint4 o;
                if (yok && (unsigned)px < (unsigned)WM) {
                    const float4* p = (const float4*)(xrow + (size_t)px * DIMC + k8 * 8);
                    float4 fa = p[0], fb = p[1];
                    o = make_uint4(cvtpk(fa.x, fa.y), cvtpk(fa.z, fa.w),
                                   cvtpk(fb.x, fb.y), cvtpk(fb.z, fb.w));
                } else {
                    o = make_uint4(0u, 0u, 0u, 0u);
                }
                *(uint4*)(sm.X + row * XT_LD + ((k8 ^ (row & 7)) * 8)) = o;
            }
        }
        __syncthreads();
        // ---- 12 chunks: load B (compile-time offsets) then 16 MFMA ----
#pragma unroll
        for (int cc = 0; cc < 12; cc++) {
            int kx = cc >> 2, c4 = cc & 3;
            int wo = (ky * 3 + kx) * 128 + c4 * 32;
            v8s bB[4];
#pragma unroll
            for (int nj = 0; nj < 4; nj++)
                bB[nj] = *(const v8s*)(wrb[nj] + wo);
            int xr7 = (l16 + kx) & 7;
            const u16* xb = sm.X + (l16 + kx) * XT_LD;
            int xo = (((c4 * 4 + lk) ^ xr7) * 8);
            v8s av[4];
#pragma unroll
            for (int mi = 0; mi < 4; mi++)
                av[mi] = *(const v8s*)(xb + mi * 16 * XT_LD + xo);
#pragma unroll
            for (int mi = 0; mi < 4; mi++)
#pragma unroll
                for (int nj = 0; nj < 4; nj++)
                    acc[mi][nj] = __builtin_amdgcn_mfma_f32_16x16x32_bf16(
                        av[mi], bB[nj], acc[mi][nj], 0, 0, 0);
        }
    }
    __syncthreads();   // conv done; X dead, epilogue tiles alias

    float bb[4];
#pragma unroll
    for (int nj = 0; nj < 4; nj++)
        bb[nj] = (w_conv ? bfx : bcatL)[cob + w_co * 64 + nj * 16 + l16];

    if (w_conv == 0) {
        // ---- per-pixel softmax over 64 g, fully in registers (verified) ----
#pragma unroll
        for (int mi = 0; mi < 4; mi++) {
#pragma unroll
            for (int q = 0; q < 4; q++) {
                float m = acc[mi][0][q] + bb[0];
#pragma unroll
                for (int nj = 1; nj < 4; nj++) m = fmaxf(m, acc[mi][nj][q] + bb[nj]);
                m = fmaxf(m, __shfl_xor(m, 1));
                m = fmaxf(m, __shfl_xor(m, 2));
                m = fmaxf(m, __shfl_xor(m, 4));
                m = fmaxf(m, __shfl_xor(m, 8));
                float ssum = 0.f;
#pragma unroll
                for (int nj = 0; nj < 4; nj++) {
                    float e = __expf(acc[mi][nj][q] + bb[nj] - m);
                    acc[mi][nj][q] = e; ssum += e;
                }
                ssum += __shfl_xor(ssum, 1);
                ssum += __shfl_xor(ssum, 2);
                ssum += __shfl_xor(ssum, 4);
                ssum += __shfl_xor(ssum, 8);
                float inv = 1.f / ssum;
#pragma unroll
                for (int nj = 0; nj < 4; nj++) acc[mi][nj][q] *= inv;
            }
        }
        // ---- slice_norm: reduce over wave's 64 px, 4 atomics/wave ----
#pragma unroll
        for (int nj = 0; nj < 4; nj++) {
            float pn = 0.f;
#pragma unroll
            for (int mi = 0; mi < 4; mi++)
#pragma unroll
                for (int q = 0; q < 4; q++) pn += acc[mi][nj][q];
            pn += __shfl_xor(pn, 16);
            pn += __shfl_xor(pn, 32);
            if (lk == 0)
                atomicAdd(&norm[(size_t)(b * HEADS + 2 * ct + w_co) * GS + nj * 16 + l16], pn);
        }
    }

    // ---- 2 single-head epilogue rounds ----
#pragma unroll
    for (int hp = 0; hp < 2; hp++) {
        bool mine = (w_co == hp);
        if (mine) {
            // scatter: L wave -> SwT[g][px], F wave -> FxT[dh][px] (swizzled)
#pragma unroll
            for (int nj = 0; nj < 4; nj++) {
                int grow = nj * 16 + l16;
                int r7 = l16 & 7;
#pragma unroll
                for (int mi = 0; mi < 4; mi++) {
                    int off = (((mi * 2 + (lk >> 1)) ^ r7) * 8) + (lk & 1) * 4;
                    uint2 wv;
                    if (w_conv == 0) {
                        wv.x = cvtpk(acc[mi][nj][0], acc[mi][nj][1]);
                        wv.y = cvtpk(acc[mi][nj][2], acc[mi][nj][3]);
                        *(uint2*)&sm.e.SwT[grow][off] = wv;
                    } else {
                        wv.x = cvtpk(acc[mi][nj][0] + bb[nj], acc[mi][nj][1] + bb[nj]);
                        wv.y = cvtpk(acc[mi][nj][2] + bb[nj], acc[mi][nj][3] + bb[nj]);
                        *(uint2*)&sm.e.FxT[grow][off] = wv;
                    }
                }
            }
        }
        __syncthreads();
        if (mine) {
            // pooling MFMA: pacc[g][dh] += sum_px SwT[g][px] * FxT[dh][px]
            // pool_half = w_conv: L wave g 0..31, F wave g 32..63; K = 64 px
            v4f pacc[2][4];
#pragma unroll
            for (int i = 0; i < 2; i++)
#pragma unroll
                for (int j = 0; j < 4; j++) pacc[i][j] = v4f{0.f, 0.f, 0.f, 0.f};
            int r7 = l16 & 7;
#pragma unroll
            for (int c = 0; c < 2; c++) {
                int ko = (((c * 4 + lk) ^ r7) * 8);
                v8s aw[2], bw[4];
#pragma unroll
                for (int mi = 0; mi < 2; mi++)
                    aw[mi] = *(const v8s*)(&sm.e.SwT[w_conv * 32 + mi * 16 + l16][0] + ko);
#pragma unroll
                for (int nj = 0; nj < 4; nj++)
                    bw[nj] = *(const v8s*)(&sm.e.FxT[nj * 16 + l16][0] + ko);
#pragma unroll
                for (int mi = 0; mi < 2; mi++)
#pragma unroll
                    for (int nj = 0; nj < 4; nj++)
                        pacc[mi][nj] = __builtin_amdgcn_mfma_f32_16x16x32_bf16(
                            aw[mi], bw[nj], pacc[mi][nj], 0, 0, 0);
            }
            int bh2 = b * HEADS + 2 * ct + hp;
#pragma unroll
            for (int mi = 0; mi < 2; mi++)
#pragma unroll
                for (int nj = 0; nj < 4; nj++)
#pragma unroll
                    for (int q = 0; q < 4; q++) {
                        int g = w_conv * 32 + mi * 16 + lk * 4 + q;
                        int dh = nj * 16 + l16;
                        atomicAdd(&straw[((size_t)bh2 * GS + g) * DH + dh], pacc[mi][nj][q]);
                    }
        }
        // swbT store: [bh][g][n], all 4 waves, 512 x 16B chunks
#pragma unroll
        for (int it = 0; it < 2; it++) {
            int chunk = it * 256 + t;     // 0..511
            int gi = chunk >> 3;          // 0..63
            int p8 = chunk & 7;
            uint4 v = *(const uint4*)(&sm.e.SwT[gi][0] + ((p8 ^ (gi & 7)) * 8));
            size_t di = (((size_t)(b * HEADS + 2 * ct + hp) * GS + gi) * NPIX)
                        + (size_t)y * WM + half * 64 + p8 * 8;
            *(uint4*)&swbT[di] = v;
        }
        __syncthreads();   // SwT/FxT reused next round
    }
}

// ---------------------------------------------------------------------------
// K4: per-(b,h) attention -> M1 (unchanged, verified).
// ---------------------------------------------------------------------------
__global__ __launch_bounds__(256) void k_attn(
    const float* __restrict__ straw, const float* __restrict__ norm,
    const float* __restrict__ wq, const float* __restrict__ wk, const float* __restrict__ wv,
    const float* __restrict__ outw, float* __restrict__ m1)
{
    __shared__ float lds[4][64][64];
    int bh = blockIdx.x, h = bh & 7;
    int t = threadIdx.x;
    for (int i = t; i < 4096; i += 256) {
        int g = i >> 6;
        lds[0][g][i & 63] = straw[(size_t)bh * 4096 + i] / (norm[bh * 64 + g] + 1e-5f);
    }
    __syncthreads();
    int g = t >> 2, d0 = (t & 3) << 4;
    for (int d = d0; d < d0 + 16; d++) {
        float sq = 0.f, sk = 0.f, sv = 0.f;
        for (int c = 0; c < 64; c++) {
            float sc = lds[0][g][c];
            sq = fmaf(sc, wq[d * 64 + c], sq);
            sk = fmaf(sc, wk[d * 64 + c], sk);
            sv = fmaf(sc, wv[d * 64 + c], sv);
        }
        lds[1][g][d] = sq; lds[2][g][d] = sk; lds[3][g][d] = sv;
    }
    __syncthreads();
    float attnrow[16];
    for (int k2 = d0, i = 0; k2 < d0 + 16; k2++, i++) {
        float s = 0.f;
        for (int d = 0; d < 64; d++) s = fmaf(lds[1][g][d], lds[2][k2][d], s);
        attnrow[i] = s * 0.125f;
    }
    __syncthreads();
    for (int i = 0; i < 16; i++) lds[0][g][d0 + i] = attnrow[i];
    __syncthreads();
    if (t < 64) {
        float mx = -1e30f;
        for (int j = 0; j < 64; j++) mx = fmaxf(mx, lds[0][t][j]);
        float s = 0.f;
        for (int j = 0; j < 64; j++) { float e = __expf(lds[0][t][j] - mx); lds[0][t][j] = e; s += e; }
        float inv = 1.f / s;
        for (int j = 0; j < 64; j++) lds[0][t][j] *= inv;
    }
    __syncthreads();
    float osrow[16];
    for (int d = d0, i = 0; d < d0 + 16; d++, i++) {
        float s = 0.f;
        for (int kx = 0; kx < 64; kx++) s = fmaf(lds[0][g][kx], lds[3][kx][d], s);
        osrow[i] = s;
    }
    __syncthreads();
    for (int i = 0; i < 16; i++) lds[2][g][d0 + i] = osrow[i];
    __syncthreads();
    int dimb = (t & 3) << 5;
    for (int dim = dimb; dim < dimb + 32; dim++) {
        float s = 0.f;
        for (int c = 0; c < 64; c++)
            s = fmaf(lds[2][g][c], outw[(size_t)dim * INNER + h * 64 + c], s);
        m1[((size_t)bh * 64 + g) * DIMC + dim] = s;
    }
}

// ---------------------------------------------------------------------------
// K5: out[b][n][d] = sum_{h,g} swT[bh][g][n] * M1[bh][g][d] + out_b[d]
// (unchanged, verified).
// ---------------------------------------------------------------------------
__global__ __launch_bounds__(256) void k_final(
    const u16* __restrict__ swbT, const float* __restrict__ m1,
    const float* __restrict__ outb, float* __restrict__ out)
{
    __shared__ float As[32][68];    // sw^T: [g][n]
    __shared__ float Bs[32][128];   // M1:   [g][d]
    int b = blockIdx.x, nt = blockIdx.y;
    int t = threadIdx.x;
    int tn = t & 15, tm = t >> 4;
    float acc[4][8];
#pragma unroll
    for (int i = 0; i < 4; i++)
#pragma unroll
        for (int j = 0; j < 8; j++) acc[i][j] = 0.f;
    int n0 = nt * 64;
    int gg = t >> 3, nq = (t & 7) * 8;
    int g2 = t >> 3, dd = (t & 7) * 16;
    for (int h = 0; h < HEADS; h++) {
        const u16* swp = swbT + (size_t)(b * HEADS + h) * GS * NPIX;
        const float* m1p = m1 + (size_t)(b * HEADS + h) * GS * DIMC;
        for (int g0 = 0; g0 < 64; g0 += 32) {
            __syncthreads();
            BF8 av8; av8.v = *(const uint4*)&swp[(size_t)(g0 + gg) * NPIX + n0 + nq];
#pragma unroll
            for (int i = 0; i < 8; i++) As[gg][nq + i] = bf2f(av8.s[i]);
            const float* bp = m1p + (size_t)(g0 + g2) * DIMC + dd;
            *(float4*)&Bs[g2][dd + 0]  = *(const float4*)(bp + 0);
            *(float4*)&Bs[g2][dd + 4]  = *(const float4*)(bp + 4);
            *(float4*)&Bs[g2][dd + 8]  = *(const float4*)(bp + 8);
            *(float4*)&Bs[g2][dd + 12] = *(const float4*)(bp + 12);
            __syncthreads();
#pragma unroll
            for (int kk = 0; kk < 32; kk++) {
                float4 a = *(const float4*)&As[kk][tm * 4];
                float4 b0 = *(const float4*)&Bs[kk][tn * 4];
                float4 b1 = *(const float4*)&Bs[kk][tn * 4 + 64];
                float av[4] = {a.x, a.y, a.z, a.w};
                float bv[8] = {b0.x, b0.y, b0.z, b0.w, b1.x, b1.y, b1.z, b1.w};
#pragma unroll
                for (int i = 0; i < 4; i++)
#pragma unroll
                    for (int j = 0; j < 8; j++)
                        acc[i][j] = fmaf(av[i], bv[j], acc[i][j]);
            }
        }
    }
    float4 bias0 = *(const float4*)&outb[tn * 4];
    float4 bias1 = *(const float4*)&outb[64 + tn * 4];
#pragma unroll
    for (int i = 0; i < 4; i++) {
        size_t n = (size_t)n0 + tm * 4 + i;
        size_t rb = ((size_t)b * NPIX + n) * DIMC;
        float4 r0, r1;
        r0.x = acc[i][0] + bias0.x; r0.y = acc[i][1] + bias0.y;
        r0.z = acc[i][2] + bias0.z; r0.w = acc[i][3] + bias0.w;
        r1.x = acc[i][4] + bias1.x; r1.y = acc[i][5] + bias1.y;
        r1.z = acc[i][6] + bias1.z; r1.w = acc[i][7] + bias1.w;
        *(float4*)&out[rb + tn * 4] = r0;
        *(float4*)&out[rb + 64 + tn * 4] = r1;
    }
}

// ---------------------------------------------------------------------------
extern "C" void kernel_launch(void* const* d_in, const int* in_sizes, int n_in,
                              void* d_out, int out_size, void* d_ws, size_t ws_size,
                              hipStream_t stream)
{
    (void)in_sizes; (void)n_in; (void)out_size;
    const float* x    = (const float*)d_in[0];
    const float* wfx  = (const float*)d_in[1];
    const float* bfx  = (const float*)d_in[2];
    const float* wx   = (const float*)d_in[3];
    const float* bx   = (const float*)d_in[4];
    const float* slw  = (const float*)d_in[5];
    const float* slb  = (const float*)d_in[6];
    const float* temp = (const float*)d_in[7];
    const float* wq   = (const float*)d_in[8];
    const float* wk   = (const float*)d_in[9];
    const float* wv   = (const float*)d_in[10];
    const float* outw = (const float*)d_in[11];
    const float* outb = (const float*)d_in[12];
    float* out = (float*)d_out;
    float* W = (float*)d_ws;

    // workspace layout (float offsets) — identical footprint to verified round-5
    u16*   wcatT = (u16*)W;               // 589,824 u16
    u16*   wfxT  = (u16*)(W + 294912);    // 589,824 u16
    float* bcatL = W + 589824;            //       512
    float* norm  = W + 590336;            //     4,096   (zeroed)
    float* straw = W + 594432;            //   262,144   (zeroed, contiguous w/ norm)
    float* m1    = W + 856576;            //   524,288
    u16*   swbT  = (u16*)(W + 1380864);   // 67,108,864 u16 = 128 MiB, [bh][g][n]
    const size_t need = 1380864ull * 4 + 67108864ull * 2;   // 139,741,184 B
    if (ws_size < need) return;

    hipMemsetAsync(norm, 0, (4096 + 262144) * sizeof(float), stream);

    k_build_w<<<dim3(1152), 256, 0, stream>>>(wx, wfx, slw, temp, wcatT, wfxT);
    k_build_b<<<dim3(1), 512, 0, stream>>>(bx, slw, slb, temp, bcatL);
    k_conv2<<<dim3(8192), 256, 0, stream>>>(x, wcatT, wfxT, bcatL, bfx, swbT, straw, norm);
    k_attn<<<dim3(64), 256, 0, stream>>>(straw, norm, wq, wk, wv, outw, m1);
    k_final<<<dim3(8, 256), 256, 0, stream>>>(swbT, m1, outb, out);
}

// Round 7
// 1161.572 us; speedup vs baseline: 1.0575x; 1.0575x over previous
//
#include <hip/hip_runtime.h>
#include <stdint.h>

#define BATCH 8
#define HEADS 8
#define HM 128
#define WM 128
#define NPIX (HM*WM)      // 16384
#define DIMC 128
#define DH 64
#define GS 64
#define INNER 512
#define KTOT 1152         // 9*128 folded conv K (36 chunks of 32)
#define XT_LD 128         // bf16 X row: NO pad; XOR swizzle supplies bank spread

typedef unsigned short u16;
typedef short v8s __attribute__((ext_vector_type(8)));   // 8 bf16 in 4 VGPRs
typedef float v4f __attribute__((ext_vector_type(4)));   // MFMA accum

__device__ __forceinline__ u16 f2bf(float f) {
    unsigned x = __float_as_uint(f);
    return (u16)((x + 0x7fffu + ((x >> 16) & 1u)) >> 16);   // RNE
}
__device__ __forceinline__ float bf2f(u16 u) { return __uint_as_float(((unsigned)u) << 16); }
__device__ __forceinline__ unsigned cvtpk(float lo, float hi) {   // HW RNE pack: {hi,lo}
    unsigned r;
    asm("v_cvt_pk_bf16_f32 %0, %1, %2" : "=v"(r) : "v"(lo), "v"(hi));
    return r;
}

union BF8 { uint4 v; u16 s[8]; };

// ---------------------------------------------------------------------------
// Build folded logit weights, TRANSPOSED + bf16 (unchanged, verified).
// ---------------------------------------------------------------------------
__global__ __launch_bounds__(256) void k_build_w(
    const float* __restrict__ wx, const float* __restrict__ wfx,
    const float* __restrict__ slw, const float* __restrict__ temp,
    u16* __restrict__ wcatT, u16* __restrict__ wfxT)
{
    __shared__ float sw_l[GS][DH + 1];
    __shared__ float wx_l[INNER];
    int row = blockIdx.x;            // 0..1151
    int t = threadIdx.x;
    for (int i = t; i < GS * DH; i += 256) sw_l[i >> 6][i & 63] = slw[i];
    for (int i = t; i < INNER; i += 256) wx_l[i] = wx[(size_t)row * INNER + i];
    __syncthreads();
#pragma unroll
    for (int j = 0; j < 2; j++) {
        int co = j * 256 + t;
        int h = co >> 6, g = co & 63;
        float s = 0.f;
        for (int c = 0; c < DH; c++) s = fmaf(wx_l[h * 64 + c], sw_l[g][c], s);
        float tv = fminf(fmaxf(temp[h], 0.1f), 5.0f);
        wcatT[(size_t)co * KTOT + row] = f2bf(s / tv);
        wfxT[(size_t)co * KTOT + row] = f2bf(wfx[(size_t)row * INNER + co]);
    }
}

__global__ __launch_bounds__(512) void k_build_b(
    const float* __restrict__ bx, const float* __restrict__ slw,
    const float* __restrict__ slb, const float* __restrict__ temp,
    float* __restrict__ bcatL)
{
    int co = threadIdx.x;            // 0..511
    int h = co >> 6, g = co & 63;
    float s = slb[g];
    for (int c = 0; c < DH; c++) s = fmaf(bx[h * 64 + c], slw[g * 64 + c], s);
    float tv = fminf(fmaxf(temp[h], 0.1f), 5.0f);
    bcatL[co] = s / tv;
}

// ---------------------------------------------------------------------------
// Fused conv kernel v6: 256 threads (4 waves), grid 8192 = (b, y, head),
// XCD-bijective swizzle (8 head-blocks sharing (b,y) -> same XCD, x L2-hot).
//  Wave = (px-half, conv in {L,F}): 64 px x 64 co x 1 conv -> acc 16 v4f.
//  - X: FULL 130-px row staged per ky (halves share), bf16 cvt_pk, XOR swz.
//  - B: per-lane global loads (L2-hot weights), linear chunk offset
//    wo = gidx*32, 1-DEEP REGISTER PREFETCH issued BEFORE current MFMAs.
//  - __launch_bounds__(256,3): 3 independent blocks/CU, desynchronized
//    phases cover the ~250cy L2 latency (m114-style TLP + issue-early).
//  - Epilogue: verified softmax-in-regs (L waves); scatter SwT/FxT;
//    pool MFMA K=128 (wave = 16-g strip); swbT rows 256 B contiguous.
// ---------------------------------------------------------------------------
union SmemC {
    u16 X[130 * XT_LD];                                     // 33,280 B
    struct { u16 SwT[64][128]; u16 FxT[64][128]; } e;       // 32,768 B
};

__global__ __launch_bounds__(256, 3) void k_conv2(
    const float* __restrict__ xin, const u16* __restrict__ wcatT,
    const u16* __restrict__ wfxT, const float* __restrict__ bcatL,
    const float* __restrict__ bfx, u16* __restrict__ swbT,
    float* __restrict__ straw, float* __restrict__ norm)
{
    __shared__ SmemC sm;
    int bid = blockIdx.x;
    int swz = (bid & 7) * 1024 + (bid >> 3);   // bijective: 8192 = 8*1024
    int b = swz >> 10;
    int r = swz & 1023;
    int y = r >> 3, h = r & 7;                 // head varies fastest in-XCD
    int cob = h << 6;                          // 64 channels of this head
    int t = threadIdx.x;
    int lane = t & 63, wave = t >> 6;
    int half = wave >> 1, w_conv = wave & 1;   // L=0, F=1
    int l16 = lane & 15, lk = lane >> 4;
    int bh = b * HEADS + h;

    v4f acc[4][4];
#pragma unroll
    for (int i = 0; i < 4; i++)
#pragma unroll
        for (int j = 0; j < 4; j++) acc[i][j] = v4f{0.f, 0.f, 0.f, 0.f};

    // lane-resolved B row base pointers (per nj), table chosen per wave
    const u16* wT = w_conv ? wfxT : wcatT;
    const u16* wrb[4];
#pragma unroll
    for (int nj = 0; nj < 4; nj++)
        wrb[nj] = wT + (size_t)(cob + nj * 16 + l16) * KTOT + lk * 8;

    // 1-deep register prefetch of B chunks (wo = gidx*32, gidx 0..35)
    v8s bB[2][4];
#pragma unroll
    for (int nj = 0; nj < 4; nj++) bB[0][nj] = *(const v8s*)(wrb[nj]);

#pragma unroll
    for (int ky = 0; ky < 3; ky++) {
        int yy = y + ky - 1;
        bool yok = (unsigned)yy < (unsigned)HM;
        const float* xrow = xin + ((size_t)b * NPIX + (size_t)yy * WM) * DIMC;
        if (ky) __syncthreads();     // previous ky's fragment readers done
        // ---- stage X(ky): 130 rows x 16 slots of 16B bf16 ----
#pragma unroll
        for (int it = 0; it < 9; it++) {
            int i = t + it * 256;
            if (i < 2080) {
                int row = i >> 4, k8 = i & 15;
                int px = row - 1;
                uint4 o;
                if (yok && (unsigned)px < (unsigned)WM) {
                    const float4* p = (const float4*)(xrow + (size_t)px * DIMC + k8 * 8);
                    float4 fa = p[0], fb = p[1];
                    o = make_uint4(cvtpk(fa.x, fa.y), cvtpk(fa.z, fa.w),
                                   cvtpk(fb.x, fb.y), cvtpk(fb.z, fb.w));
                } else {
                    o = make_uint4(0u, 0u, 0u, 0u);
                }
                *(uint4*)(sm.X + row * XT_LD + ((k8 ^ (row & 7)) * 8)) = o;
            }
        }
        __syncthreads();
        // ---- 12 chunks: issue B(gidx+1) loads FIRST, then MFMA(gidx) ----
#pragma unroll
        for (int cc = 0; cc < 12; cc++) {
            int gidx = ky * 12 + cc;
            if (gidx < 35) {
#pragma unroll
                for (int nj = 0; nj < 4; nj++)
                    bB[(gidx + 1) & 1][nj] = *(const v8s*)(wrb[nj] + (gidx + 1) * 32);
            }
            int kx = cc >> 2, c4 = cc & 3;
            int xr7 = (l16 + kx) & 7;
            const u16* xb = sm.X + (half * 64 + l16 + kx) * XT_LD;
            int xo = (((c4 * 4 + lk) ^ xr7) * 8);
            v8s av[4];
#pragma unroll
            for (int mi = 0; mi < 4; mi++)
                av[mi] = *(const v8s*)(xb + mi * 16 * XT_LD + xo);
#pragma unroll
            for (int mi = 0; mi < 4; mi++)
#pragma unroll
                for (int nj = 0; nj < 4; nj++)
                    acc[mi][nj] = __builtin_amdgcn_mfma_f32_16x16x32_bf16(
                        av[mi], bB[gidx & 1][nj], acc[mi][nj], 0, 0, 0);
        }
    }
    __syncthreads();   // conv done; X dead, epilogue tiles alias

    float bb[4];
#pragma unroll
    for (int nj = 0; nj < 4; nj++)
        bb[nj] = (w_conv ? bfx : bcatL)[cob + nj * 16 + l16];

    if (w_conv == 0) {
        // ---- per-pixel softmax over 64 g, fully in registers (verified) ----
#pragma unroll
        for (int mi = 0; mi < 4; mi++) {
#pragma unroll
            for (int q = 0; q < 4; q++) {
                float m = acc[mi][0][q] + bb[0];
#pragma unroll
                for (int nj = 1; nj < 4; nj++) m = fmaxf(m, acc[mi][nj][q] + bb[nj]);
                m = fmaxf(m, __shfl_xor(m, 1));
                m = fmaxf(m, __shfl_xor(m, 2));
                m = fmaxf(m, __shfl_xor(m, 4));
                m = fmaxf(m, __shfl_xor(m, 8));
                float ssum = 0.f;
#pragma unroll
                for (int nj = 0; nj < 4; nj++) {
                    float e = __expf(acc[mi][nj][q] + bb[nj] - m);
                    acc[mi][nj][q] = e; ssum += e;
                }
                ssum += __shfl_xor(ssum, 1);
                ssum += __shfl_xor(ssum, 2);
                ssum += __shfl_xor(ssum, 4);
                ssum += __shfl_xor(ssum, 8);
                float inv = 1.f / ssum;
#pragma unroll
                for (int nj = 0; nj < 4; nj++) acc[mi][nj][q] *= inv;
            }
        }
        // ---- slice_norm: reduce over wave's 64 px, 4 atomics/wave ----
#pragma unroll
        for (int nj = 0; nj < 4; nj++) {
            float pn = 0.f;
#pragma unroll
            for (int mi = 0; mi < 4; mi++)
#pragma unroll
                for (int q = 0; q < 4; q++) pn += acc[mi][nj][q];
            pn += __shfl_xor(pn, 16);
            pn += __shfl_xor(pn, 32);
            if (lk == 0)
                atomicAdd(&norm[(size_t)bh * GS + nj * 16 + l16], pn);
        }
    }

    // ---- scatter: L -> SwT[g][128px], F -> FxT[dh][128px] (swizzled) ----
    // px = half*64 + mi*16 + lk*4 + q;  octet p8 = half*8 + mi*2 + (lk>>1)
#pragma unroll
    for (int nj = 0; nj < 4; nj++) {
        int grow = nj * 16 + l16;
        int r7 = l16 & 7;
#pragma unroll
        for (int mi = 0; mi < 4; mi++) {
            int p8 = half * 8 + mi * 2 + (lk >> 1);
            int off = ((p8 ^ r7) * 8) + (lk & 1) * 4;
            uint2 wv;
            if (w_conv == 0) {
                wv.x = cvtpk(acc[mi][nj][0], acc[mi][nj][1]);
                wv.y = cvtpk(acc[mi][nj][2], acc[mi][nj][3]);
                *(uint2*)&sm.e.SwT[grow][off] = wv;
            } else {
                wv.x = cvtpk(acc[mi][nj][0] + bb[nj], acc[mi][nj][1] + bb[nj]);
                wv.y = cvtpk(acc[mi][nj][2] + bb[nj], acc[mi][nj][3] + bb[nj]);
                *(uint2*)&sm.e.FxT[grow][off] = wv;
            }
        }
    }
    __syncthreads();

    // ---- pooling MFMA: pacc[g][dh] += sum_px SwT[g][px]*FxT[dh][px] ----
    // wave owns g-strip [wave*16, wave*16+16); K = 128 px (4 k-chunks)
    {
        v4f pacc[4];
#pragma unroll
        for (int j = 0; j < 4; j++) pacc[j] = v4f{0.f, 0.f, 0.f, 0.f};
        int ga = wave * 16 + l16;
        int ra = ga & 7;
#pragma unroll
        for (int c = 0; c < 4; c++) {
            v8s aw = *(const v8s*)(&sm.e.SwT[ga][0] + (((c * 4 + lk) ^ ra) * 8));
            v8s bw[4];
#pragma unroll
            for (int nj = 0; nj < 4; nj++) {
                int dr = nj * 16 + l16;
                bw[nj] = *(const v8s*)(&sm.e.FxT[dr][0] + (((c * 4 + lk) ^ (dr & 7)) * 8));
            }
#pragma unroll
            for (int nj = 0; nj < 4; nj++)
                pacc[nj] = __builtin_amdgcn_mfma_f32_16x16x32_bf16(
                    aw, bw[nj], pacc[nj], 0, 0, 0);
        }
#pragma unroll
        for (int nj = 0; nj < 4; nj++)
#pragma unroll
            for (int q = 0; q < 4; q++) {
                int g = wave * 16 + lk * 4 + q;
                int dh = nj * 16 + l16;
                atomicAdd(&straw[((size_t)bh * GS + g) * DH + dh], pacc[nj][q]);
            }
    }

    // ---- swbT store: [bh][g][n], 256 B contiguous per g row ----
#pragma unroll
    for (int it = 0; it < 4; it++) {
        int chunk = it * 256 + t;     // 0..1023
        int gi = chunk >> 4;          // 0..63
        int p8 = chunk & 15;
        uint4 v = *(const uint4*)(&sm.e.SwT[gi][0] + ((p8 ^ (gi & 7)) * 8));
        size_t di = (((size_t)bh * GS + gi) * NPIX) + (size_t)y * WM + p8 * 8;
        *(uint4*)&swbT[di] = v;
    }
}

// ---------------------------------------------------------------------------
// K4: per-(b,h) attention -> M1 (unchanged, verified).
// ---------------------------------------------------------------------------
__global__ __launch_bounds__(256) void k_attn(
    const float* __restrict__ straw, const float* __restrict__ norm,
    const float* __restrict__ wq, const float* __restrict__ wk, const float* __restrict__ wv,
    const float* __restrict__ outw, float* __restrict__ m1)
{
    __shared__ float lds[4][64][64];
    int bh = blockIdx.x, h = bh & 7;
    int t = threadIdx.x;
    for (int i = t; i < 4096; i += 256) {
        int g = i >> 6;
        lds[0][g][i & 63] = straw[(size_t)bh * 4096 + i] / (norm[bh * 64 + g] + 1e-5f);
    }
    __syncthreads();
    int g = t >> 2, d0 = (t & 3) << 4;
    for (int d = d0; d < d0 + 16; d++) {
        float sq = 0.f, sk = 0.f, sv = 0.f;
        for (int c = 0; c < 64; c++) {
            float sc = lds[0][g][c];
            sq = fmaf(sc, wq[d * 64 + c], sq);
            sk = fmaf(sc, wk[d * 64 + c], sk);
            sv = fmaf(sc, wv[d * 64 + c], sv);
        }
        lds[1][g][d] = sq; lds[2][g][d] = sk; lds[3][g][d] = sv;
    }
    __syncthreads();
    float attnrow[16];
    for (int k2 = d0, i = 0; k2 < d0 + 16; k2++, i++) {
        float s = 0.f;
        for (int d = 0; d < 64; d++) s = fmaf(lds[1][g][d], lds[2][k2][d], s);
        attnrow[i] = s * 0.125f;
    }
    __syncthreads();
    for (int i = 0; i < 16; i++) lds[0][g][d0 + i] = attnrow[i];
    __syncthreads();
    if (t < 64) {
        float mx = -1e30f;
        for (int j = 0; j < 64; j++) mx = fmaxf(mx, lds[0][t][j]);
        float s = 0.f;
        for (int j = 0; j < 64; j++) { float e = __expf(lds[0][t][j] - mx); lds[0][t][j] = e; s += e; }
        float inv = 1.f / s;
        for (int j = 0; j < 64; j++) lds[0][t][j] *= inv;
    }
    __syncthreads();
    float osrow[16];
    for (int d = d0, i = 0; d < d0 + 16; d++, i++) {
        float s = 0.f;
        for (int kx = 0; kx < 64; kx++) s = fmaf(lds[0][g][kx], lds[3][kx][d], s);
        osrow[i] = s;
    }
    __syncthreads();
    for (int i = 0; i < 16; i++) lds[2][g][d0 + i] = osrow[i];
    __syncthreads();
    int dimb = (t & 3) << 5;
    for (int dim = dimb; dim < dimb + 32; dim++) {
        float s = 0.f;
        for (int c = 0; c < 64; c++)
            s = fmaf(lds[2][g][c], outw[(size_t)dim * INNER + h * 64 + c], s);
        m1[((size_t)bh * 64 + g) * DIMC + dim] = s;
    }
}

// ---------------------------------------------------------------------------
// K5: out[b][n][d] = sum_{h,g} swT[bh][g][n] * M1[bh][g][d] + out_b[d]
// (unchanged, verified).
// ---------------------------------------------------------------------------
__global__ __launch_bounds__(256) void k_final(
    const u16* __restrict__ swbT, const float* __restrict__ m1,
    const float* __restrict__ outb, float* __restrict__ out)
{
    __shared__ float As[32][68];    // sw^T: [g][n]
    __shared__ float Bs[32][128];   // M1:   [g][d]
    int b = blockIdx.x, nt = blockIdx.y;
    int t = threadIdx.x;
    int tn = t & 15, tm = t >> 4;
    float acc[4][8];
#pragma unroll
    for (int i = 0; i < 4; i++)
#pragma unroll
        for (int j = 0; j < 8; j++) acc[i][j] = 0.f;
    int n0 = nt * 64;
    int gg = t >> 3, nq = (t & 7) * 8;
    int g2 = t >> 3, dd = (t & 7) * 16;
    for (int h = 0; h < HEADS; h++) {
        const u16* swp = swbT + (size_t)(b * HEADS + h) * GS * NPIX;
        const float* m1p = m1 + (size_t)(b * HEADS + h) * GS * DIMC;
        for (int g0 = 0; g0 < 64; g0 += 32) {
            __syncthreads();
            BF8 av8; av8.v = *(const uint4*)&swp[(size_t)(g0 + gg) * NPIX + n0 + nq];
#pragma unroll
            for (int i = 0; i < 8; i++) As[gg][nq + i] = bf2f(av8.s[i]);
            const float* bp = m1p + (size_t)(g0 + g2) * DIMC + dd;
            *(float4*)&Bs[g2][dd + 0]  = *(const float4*)(bp + 0);
            *(float4*)&Bs[g2][dd + 4]  = *(const float4*)(bp + 4);
            *(float4*)&Bs[g2][dd + 8]  = *(const float4*)(bp + 8);
            *(float4*)&Bs[g2][dd + 12] = *(const float4*)(bp + 12);
            __syncthreads();
#pragma unroll
            for (int kk = 0; kk < 32; kk++) {
                float4 a = *(const float4*)&As[kk][tm * 4];
                float4 b0 = *(const float4*)&Bs[kk][tn * 4];
                float4 b1 = *(const float4*)&Bs[kk][tn * 4 + 64];
                float av[4] = {a.x, a.y, a.z, a.w};
                float bv[8] = {b0.x, b0.y, b0.z, b0.w, b1.x, b1.y, b1.z, b1.w};
#pragma unroll
                for (int i = 0; i < 4; i++)
#pragma unroll
                    for (int j = 0; j < 8; j++)
                        acc[i][j] = fmaf(av[i], bv[j], acc[i][j]);
            }
        }
    }
    float4 bias0 = *(const float4*)&outb[tn * 4];
    float4 bias1 = *(const float4*)&outb[64 + tn * 4];
#pragma unroll
    for (int i = 0; i < 4; i++) {
        size_t n = (size_t)n0 + tm * 4 + i;
        size_t rb = ((size_t)b * NPIX + n) * DIMC;
        float4 r0, r1;
        r0.x = acc[i][0] + bias0.x; r0.y = acc[i][1] + bias0.y;
        r0.z = acc[i][2] + bias0.z; r0.w = acc[i][3] + bias0.w;
        r1.x = acc[i][4] + bias1.x; r1.y = acc[i][5] + bias1.y;
        r1.z = acc[i][6] + bias1.z; r1.w = acc[i][7] + bias1.w;
        *(float4*)&out[rb + tn * 4] = r0;
        *(float4*)&out[rb + 64 + tn * 4] = r1;
    }
}

// ---------------------------------------------------------------------------
extern "C" void kernel_launch(void* const* d_in, const int* in_sizes, int n_in,
                              void* d_out, int out_size, void* d_ws, size_t ws_size,
                              hipStream_t stream)
{
    (void)in_sizes; (void)n_in; (void)out_size;
    const float* x    = (const float*)d_in[0];
    const float* wfx  = (const float*)d_in[1];
    const float* bfx  = (const float*)d_in[2];
    const float* wx   = (const float*)d_in[3];
    const float* bx   = (const float*)d_in[4];
    const float* slw  = (const float*)d_in[5];
    const float* slb  = (const float*)d_in[6];
    const float* temp = (const float*)d_in[7];
    const float* wq   = (const float*)d_in[8];
    const float* wk   = (const float*)d_in[9];
    const float* wv   = (const float*)d_in[10];
    const float* outw = (const float*)d_in[11];
    const float* outb = (const float*)d_in[12];
    float* out = (float*)d_out;
    float* W = (float*)d_ws;

    // workspace layout (float offsets) — identical footprint to verified round-6
    u16*   wcatT = (u16*)W;               // 589,824 u16
    u16*   wfxT  = (u16*)(W + 294912);    // 589,824 u16
    float* bcatL = W + 589824;            //       512
    float* norm  = W + 590336;            //     4,096   (zeroed)
    float* straw = W + 594432;            //   262,144   (zeroed, contiguous w/ norm)
    float* m1    = W + 856576;            //   524,288
    u16*   swbT  = (u16*)(W + 1380864);   // 67,108,864 u16 = 128 MiB, [bh][g][n]
    const size_t need = 1380864ull * 4 + 67108864ull * 2;   // 139,741,184 B
    if (ws_size < need) return;

    hipMemsetAsync(norm, 0, (4096 + 262144) * sizeof(float), stream);

    k_build_w<<<dim3(1152), 256, 0, stream>>>(wx, wfx, slw, temp, wcatT, wfxT);
    k_build_b<<<dim3(1), 512, 0, stream>>>(bx, slw, slb, temp, bcatL);
    k_conv2<<<dim3(8192), 256, 0, stream>>>(x, wcatT, wfxT, bcatL, bfx, swbT, straw, norm);
    k_attn<<<dim3(64), 256, 0, stream>>>(straw, norm, wq, wk, wv, outw, m1);
    k_final<<<dim3(8, 256), 256, 0, stream>>>(swbT, m1, outb, out);
}

// Round 9
// 1056.846 us; speedup vs baseline: 1.1623x; 1.0991x over previous
//
#include <hip/hip_runtime.h>
#include <stdint.h>

#define BATCH 8
#define HEADS 8
#define HM 128
#define WM 128
#define NPIX (HM*WM)      // 16384
#define DIMC 128
#define DH 64
#define GS 64
#define INNER 512
#define KTOT 1152         // 9*128 folded conv K (36 chunks of 32)
#define XT_LD 128         // bf16 X row (u16 elems); swizzle via pre-swizzled src

typedef unsigned short u16;
typedef short v8s __attribute__((ext_vector_type(8)));   // 8 bf16 in 4 VGPRs
typedef float v4f __attribute__((ext_vector_type(4)));   // MFMA accum

__device__ __forceinline__ u16 f2bf(float f) {
    unsigned x = __float_as_uint(f);
    return (u16)((x + 0x7fffu + ((x >> 16) & 1u)) >> 16);   // RNE
}
__device__ __forceinline__ float bf2f(u16 u) { return __uint_as_float(((unsigned)u) << 16); }
__device__ __forceinline__ unsigned cvtpk(float lo, float hi) {   // HW RNE pack: {hi,lo}
    unsigned r;
    asm("v_cvt_pk_bf16_f32 %0, %1, %2" : "=v"(r) : "v"(lo), "v"(hi));
    return r;
}
__device__ __forceinline__ void gload16(const u16* g, u16* ldst) {
    // async global->LDS DMA, 16 B/lane; ldst = wave-uniform base (+lane*16 by HW)
    __builtin_amdgcn_global_load_lds(
        (const __attribute__((address_space(1))) void*)g,
        (__attribute__((address_space(3))) void*)ldst, 16, 0, 0);
}

union BF8 { uint4 v; u16 s[8]; };

// ---------------------------------------------------------------------------
// x fp32 -> bf16, rows PRE-SWIZZLED: storage position s = k8 ^ (rowg&7) holds
// data slot k8 (rowg&7 == px&7). RNE-identical to the verified in-kernel cvt.
// ---------------------------------------------------------------------------
__global__ __launch_bounds__(256) void k_xbf(
    const float* __restrict__ x, u16* __restrict__ xbf)
{
    int i = blockIdx.x * 256 + threadIdx.x;    // 0..2,097,151 (one 16B slot)
    int rowg = i >> 4, k8 = i & 15;
    const float* src = x + ((size_t)rowg * DIMC + k8 * 8);
    float4 fa = *(const float4*)src;
    float4 fb = *(const float4*)(src + 4);
    uint4 o = make_uint4(cvtpk(fa.x, fa.y), cvtpk(fa.z, fa.w),
                         cvtpk(fb.x, fb.y), cvtpk(fb.z, fb.w));
    int s = k8 ^ (rowg & 7);
    *(uint4*)(xbf + (size_t)rowg * DIMC + s * 8) = o;
}

// ---------------------------------------------------------------------------
// Build folded logit weights, TRANSPOSED + bf16 (unchanged, verified).
// ---------------------------------------------------------------------------
__global__ __launch_bounds__(256) void k_build_w(
    const float* __restrict__ wx, const float* __restrict__ wfx,
    const float* __restrict__ slw, const float* __restrict__ temp,
    u16* __restrict__ wcatT, u16* __restrict__ wfxT)
{
    __shared__ float sw_l[GS][DH + 1];
    __shared__ float wx_l[INNER];
    int row = blockIdx.x;            // 0..1151
    int t = threadIdx.x;
    for (int i = t; i < GS * DH; i += 256) sw_l[i >> 6][i & 63] = slw[i];
    for (int i = t; i < INNER; i += 256) wx_l[i] = wx[(size_t)row * INNER + i];
    __syncthreads();
#pragma unroll
    for (int j = 0; j < 2; j++) {
        int co = j * 256 + t;
        int h = co >> 6, g = co & 63;
        float s = 0.f;
        for (int c = 0; c < DH; c++) s = fmaf(wx_l[h * 64 + c], sw_l[g][c], s);
        float tv = fminf(fmaxf(temp[h], 0.1f), 5.0f);
        wcatT[(size_t)co * KTOT + row] = f2bf(s / tv);
        wfxT[(size_t)co * KTOT + row] = f2bf(wfx[(size_t)row * INNER + co]);
    }
}

__global__ __launch_bounds__(512) void k_build_b(
    const float* __restrict__ bx, const float* __restrict__ slw,
    const float* __restrict__ slb, const float* __restrict__ temp,
    float* __restrict__ bcatL)
{
    int co = threadIdx.x;            // 0..511
    int h = co >> 6, g = co & 63;
    float s = slb[g];
    for (int c = 0; c < DH; c++) s = fmaf(bx[h * 64 + c], slw[g * 64 + c], s);
    float tv = fminf(fmaxf(temp[h], 0.1f), 5.0f);
    bcatL[co] = s / tv;
}

// ---------------------------------------------------------------------------
// Fused conv kernel v7: identical structure to verified v6 EXCEPT the X
// staging is now pure async global_load_lds from pre-swizzled bf16 xbf:
//  - linear LDS dest (uniform base + lane*16), inverse-swizzled source,
//    XOR on read keyed (l16+kx+7)&7  (LDS row = px+1).
//  - OOB halo lanes source a 16B zero page (zbuf).
//  - one vmcnt(0)+barrier per ky; no cvt, no ds_write, no VGPR round-trip.
// ---------------------------------------------------------------------------
union SmemC {
    u16 X[132 * XT_LD];                                     // 33,792 B (2112 slots)
    struct { u16 SwT[64][128]; u16 FxT[64][128]; } e;       // 32,768 B
};

__global__ __launch_bounds__(256, 3) void k_conv2(
    const u16* __restrict__ xbf, const u16* __restrict__ wcatT,
    const u16* __restrict__ wfxT, const float* __restrict__ bcatL,
    const float* __restrict__ bfx, const u16* __restrict__ zbuf,
    u16* __restrict__ swbT, float* __restrict__ straw, float* __restrict__ norm)
{
    __shared__ SmemC sm;
    int bid = blockIdx.x;
    int swz = (bid & 7) * 1024 + (bid >> 3);   // bijective: 8192 = 8*1024
    int b = swz >> 10;
    int r = swz & 1023;
    int y = r >> 3, h = r & 7;                 // head varies fastest in-XCD
    int cob = h << 6;                          // 64 channels of this head
    int t = threadIdx.x;
    int lane = t & 63, wave = t >> 6;
    int half = wave >> 1, w_conv = wave & 1;   // L=0, F=1
    int l16 = lane & 15, lk = lane >> 4;
    int bh = b * HEADS + h;

    v4f acc[4][4];
#pragma unroll
    for (int i = 0; i < 4; i++)
#pragma unroll
        for (int j = 0; j < 4; j++) acc[i][j] = v4f{0.f, 0.f, 0.f, 0.f};

    // lane-resolved B row base pointers (per nj), table chosen per wave
    const u16* wT = w_conv ? wfxT : wcatT;
    const u16* wrb[4];
#pragma unroll
    for (int nj = 0; nj < 4; nj++)
        wrb[nj] = wT + (size_t)(cob + nj * 16 + l16) * KTOT + lk * 8;

    // 1-deep register prefetch of B chunks (wo = gidx*32, gidx 0..35)
    v8s bB[2][4];
#pragma unroll
    for (int nj = 0; nj < 4; nj++) bB[0][nj] = *(const v8s*)(wrb[nj]);

#pragma unroll
    for (int ky = 0; ky < 3; ky++) {
        int yy = y + ky - 1;
        bool yok = (unsigned)yy < (unsigned)HM;
        const u16* xrowb = xbf + ((size_t)b * NPIX + (size_t)yy * WM) * DIMC;
        if (ky) __syncthreads();     // previous ky's fragment readers done
        // ---- stage X(ky): 2080 slots via async global_load_lds ----
        for (int j = wave; j < 33; j += 4) {      // wave-uniform trip count
            int slot = j * 64 + lane;             // 0..2111 (2080..2111 pad)
            int row = slot >> 4, k8 = slot & 15;
            int px = row - 1;
            const u16* src = (yok && (unsigned)px < (unsigned)WM)
                           ? xrowb + (size_t)px * DIMC + k8 * 8 : zbuf;
            gload16(src, sm.X + j * 512);         // +lane*16 by HW
        }
        asm volatile("s_waitcnt vmcnt(0)" ::: "memory");
        __syncthreads();
        // ---- 12 chunks: issue B(gidx+1) loads FIRST, then MFMA(gidx) ----
#pragma unroll
        for (int cc = 0; cc < 12; cc++) {
            int gidx = ky * 12 + cc;
            if (gidx < 35) {
#pragma unroll
                for (int nj = 0; nj < 4; nj++)
                    bB[(gidx + 1) & 1][nj] = *(const v8s*)(wrb[nj] + (gidx + 1) * 32);
            }
            int kx = cc >> 2, c4 = cc & 3;
            int xr7 = (l16 + kx + 7) & 7;         // key = px&7, px = row-1
            const u16* xb = sm.X + (half * 64 + l16 + kx) * XT_LD;
            int xo = (((c4 * 4 + lk) ^ xr7) * 8);
            v8s av[4];
#pragma unroll
            for (int mi = 0; mi < 4; mi++)
                av[mi] = *(const v8s*)(xb + mi * 16 * XT_LD + xo);
#pragma unroll
            for (int mi = 0; mi < 4; mi++)
#pragma unroll
                for (int nj = 0; nj < 4; nj++)
                    acc[mi][nj] = __builtin_amdgcn_mfma_f32_16x16x32_bf16(
                        av[mi], bB[gidx & 1][nj], acc[mi][nj], 0, 0, 0);
        }
    }
    __syncthreads();   // conv done; X dead, epilogue tiles alias

    float bb[4];
#pragma unroll
    for (int nj = 0; nj < 4; nj++)
        bb[nj] = (w_conv ? bfx : bcatL)[cob + nj * 16 + l16];

    if (w_conv == 0) {
        // ---- per-pixel softmax over 64 g, fully in registers (verified) ----
#pragma unroll
        for (int mi = 0; mi < 4; mi++) {
#pragma unroll
            for (int q = 0; q < 4; q++) {
                float m = acc[mi][0][q] + bb[0];
#pragma unroll
                for (int nj = 1; nj < 4; nj++) m = fmaxf(m, acc[mi][nj][q] + bb[nj]);
                m = fmaxf(m, __shfl_xor(m, 1));
                m = fmaxf(m, __shfl_xor(m, 2));
                m = fmaxf(m, __shfl_xor(m, 4));
                m = fmaxf(m, __shfl_xor(m, 8));
                float ssum = 0.f;
#pragma unroll
                for (int nj = 0; nj < 4; nj++) {
                    float e = __expf(acc[mi][nj][q] + bb[nj] - m);
                    acc[mi][nj][q] = e; ssum += e;
                }
                ssum += __shfl_xor(ssum, 1);
                ssum += __shfl_xor(ssum, 2);
                ssum += __shfl_xor(ssum, 4);
                ssum += __shfl_xor(ssum, 8);
                float inv = 1.f / ssum;
#pragma unroll
                for (int nj = 0; nj < 4; nj++) acc[mi][nj][q] *= inv;
            }
        }
        // ---- slice_norm: reduce over wave's 64 px, 4 atomics/wave ----
#pragma unroll
        for (int nj = 0; nj < 4; nj++) {
            float pn = 0.f;
#pragma unroll
            for (int mi = 0; mi < 4; mi++)
#pragma unroll
                for (int q = 0; q < 4; q++) pn += acc[mi][nj][q];
            pn += __shfl_xor(pn, 16);
            pn += __shfl_xor(pn, 32);
            if (lk == 0)
                atomicAdd(&norm[(size_t)bh * GS + nj * 16 + l16], pn);
        }
    }

    // ---- scatter: L -> SwT[g][128px], F -> FxT[dh][128px] (swizzled) ----
#pragma unroll
    for (int nj = 0; nj < 4; nj++) {
        int grow = nj * 16 + l16;
        int r7 = l16 & 7;
#pragma unroll
        for (int mi = 0; mi < 4; mi++) {
            int p8 = half * 8 + mi * 2 + (lk >> 1);
            int off = ((p8 ^ r7) * 8) + (lk & 1) * 4;
            uint2 wv;
            if (w_conv == 0) {
                wv.x = cvtpk(acc[mi][nj][0], acc[mi][nj][1]);
                wv.y = cvtpk(acc[mi][nj][2], acc[mi][nj][3]);
                *(uint2*)&sm.e.SwT[grow][off] = wv;
            } else {
                wv.x = cvtpk(acc[mi][nj][0] + bb[nj], acc[mi][nj][1] + bb[nj]);
                wv.y = cvtpk(acc[mi][nj][2] + bb[nj], acc[mi][nj][3] + bb[nj]);
                *(uint2*)&sm.e.FxT[grow][off] = wv;
            }
        }
    }
    __syncthreads();

    // ---- pooling MFMA: pacc[g][dh] += sum_px SwT[g][px]*FxT[dh][px] ----
    {
        v4f pacc[4];
#pragma unroll
        for (int j = 0; j < 4; j++) pacc[j] = v4f{0.f, 0.f, 0.f, 0.f};
        int ga = wave * 16 + l16;
        int ra = ga & 7;
#pragma unroll
        for (int c = 0; c < 4; c++) {
            v8s aw = *(const v8s*)(&sm.e.SwT[ga][0] + (((c * 4 + lk) ^ ra) * 8));
            v8s bw[4];
#pragma unroll
            for (int nj = 0; nj < 4; nj++) {
                int dr = nj * 16 + l16;
                bw[nj] = *(const v8s*)(&sm.e.FxT[dr][0] + (((c * 4 + lk) ^ (dr & 7)) * 8));
            }
#pragma unroll
            for (int nj = 0; nj < 4; nj++)
                pacc[nj] = __builtin_amdgcn_mfma_f32_16x16x32_bf16(
                    aw, bw[nj], pacc[nj], 0, 0, 0);
        }
#pragma unroll
        for (int nj = 0; nj < 4; nj++)
#pragma unroll
            for (int q = 0; q < 4; q++) {
                int g = wave * 16 + lk * 4 + q;
                int dh = nj * 16 + l16;
                atomicAdd(&straw[((size_t)bh * GS + g) * DH + dh], pacc[nj][q]);
            }
    }

    // ---- swbT store: [bh][g][n], 256 B contiguous per g row ----
#pragma unroll
    for (int it = 0; it < 4; it++) {
        int chunk = it * 256 + t;     // 0..1023
        int gi = chunk >> 4;          // 0..63
        int p8 = chunk & 15;
        uint4 v = *(const uint4*)(&sm.e.SwT[gi][0] + ((p8 ^ (gi & 7)) * 8));
        size_t di = (((size_t)bh * GS + gi) * NPIX) + (size_t)y * WM + p8 * 8;
        *(uint4*)&swbT[di] = v;
    }
}

// ---------------------------------------------------------------------------
// K4: per-(b,h) attention -> M1 (unchanged, verified).
// ---------------------------------------------------------------------------
__global__ __launch_bounds__(256) void k_attn(
    const float* __restrict__ straw, const float* __restrict__ norm,
    const float* __restrict__ wq, const float* __restrict__ wk, const float* __restrict__ wv,
    const float* __restrict__ outw, float* __restrict__ m1)
{
    __shared__ float lds[4][64][64];
    int bh = blockIdx.x, h = bh & 7;
    int t = threadIdx.x;
    for (int i = t; i < 4096; i += 256) {
        int g = i >> 6;
        lds[0][g][i & 63] = straw[(size_t)bh * 4096 + i] / (norm[bh * 64 + g] + 1e-5f);
    }
    __syncthreads();
    int g = t >> 2, d0 = (t & 3) << 4;
    for (int d = d0; d < d0 + 16; d++) {
        float sq = 0.f, sk = 0.f, sv = 0.f;
        for (int c = 0; c < 64; c++) {
            float sc = lds[0][g][c];
            sq = fmaf(sc, wq[d * 64 + c], sq);
            sk = fmaf(sc, wk[d * 64 + c], sk);
            sv = fmaf(sc, wv[d * 64 + c], sv);
        }
        lds[1][g][d] = sq; lds[2][g][d] = sk; lds[3][g][d] = sv;
    }
    __syncthreads();
    float attnrow[16];
    for (int k2 = d0, i = 0; k2 < d0 + 16; k2++, i++) {
        float s = 0.f;
        for (int d = 0; d < 64; d++) s = fmaf(lds[1][g][d], lds[2][k2][d], s);
        attnrow[i] = s * 0.125f;
    }
    __syncthreads();
    for (int i = 0; i < 16; i++) lds[0][g][d0 + i] = attnrow[i];
    __syncthreads();
    if (t < 64) {
        float mx = -1e30f;
        for (int j = 0; j < 64; j++) mx = fmaxf(mx, lds[0][t][j]);
        float s = 0.f;
        for (int j = 0; j < 64; j++) { float e = __expf(lds[0][t][j] - mx); lds[0][t][j] = e; s += e; }
        float inv = 1.f / s;
        for (int j = 0; j < 64; j++) lds[0][t][j] *= inv;
    }
    __syncthreads();
    float osrow[16];
    for (int d = d0, i = 0; d < d0 + 16; d++, i++) {
        float s = 0.f;
        for (int kx = 0; kx < 64; kx++) s = fmaf(lds[0][g][kx], lds[3][kx][d], s);
        osrow[i] = s;
    }
    __syncthreads();
    for (int i = 0; i < 16; i++) lds[2][g][d0 + i] = osrow[i];
    __syncthreads();
    int dimb = (t & 3) << 5;
    for (int dim = dimb; dim < dimb + 32; dim++) {
        float s = 0.f;
        for (int c = 0; c < 64; c++)
            s = fmaf(lds[2][g][c], outw[(size_t)dim * INNER + h * 64 + c], s);
        m1[((size_t)bh * 64 + g) * DIMC + dim] = s;
    }
}

// ---------------------------------------------------------------------------
// K5: out[b][n][d] = sum_{h,g} swT[bh][g][n] * M1[bh][g][d] + out_b[d]
// (unchanged, verified).
// ---------------------------------------------------------------------------
__global__ __launch_bounds__(256) void k_final(
    const u16* __restrict__ swbT, const float* __restrict__ m1,
    const float* __restrict__ outb, float* __restrict__ out)
{
    __shared__ float As[32][68];    // sw^T: [g][n]
    __shared__ float Bs[32][128];   // M1:   [g][d]
    int b = blockIdx.x, nt = blockIdx.y;
    int t = threadIdx.x;
    int tn = t & 15, tm = t >> 4;
    float acc[4][8];
#pragma unroll
    for (int i = 0; i < 4; i++)
#pragma unroll
        for (int j = 0; j < 8; j++) acc[i][j] = 0.f;
    int n0 = nt * 64;
    int gg = t >> 3, nq = (t & 7) * 8;
    int g2 = t >> 3, dd = (t & 7) * 16;
    for (int h = 0; h < HEADS; h++) {
        const u16* swp = swbT + (size_t)(b * HEADS + h) * GS * NPIX;
        const float* m1p = m1 + (size_t)(b * HEADS + h) * GS * DIMC;
        for (int g0 = 0; g0 < 64; g0 += 32) {
            __syncthreads();
            BF8 av8; av8.v = *(const uint4*)&swp[(size_t)(g0 + gg) * NPIX + n0 + nq];
#pragma unroll
            for (int i = 0; i < 8; i++) As[gg][nq + i] = bf2f(av8.s[i]);
            const float* bp = m1p + (size_t)(g0 + g2) * DIMC + dd;
            *(float4*)&Bs[g2][dd + 0]  = *(const float4*)(bp + 0);
            *(float4*)&Bs[g2][dd + 4]  = *(const float4*)(bp + 4);
            *(float4*)&Bs[g2][dd + 8]  = *(const float4*)(bp + 8);
            *(float4*)&Bs[g2][dd + 12] = *(const float4*)(bp + 12);
            __syncthreads();
#pragma unroll
            for (int kk = 0; kk < 32; kk++) {
                float4 a = *(const float4*)&As[kk][tm * 4];
                float4 b0 = *(const float4*)&Bs[kk][tn * 4];
                float4 b1 = *(const float4*)&Bs[kk][tn * 4 + 64];
                float av[4] = {a.x, a.y, a.z, a.w};
                float bv[8] = {b0.x, b0.y, b0.z, b0.w, b1.x, b1.y, b1.z, b1.w};
#pragma unroll
                for (int i = 0; i < 4; i++)
#pragma unroll
                    for (int j = 0; j < 8; j++)
                        acc[i][j] = fmaf(av[i], bv[j], acc[i][j]);
            }
        }
    }
    float4 bias0 = *(const float4*)&outb[tn * 4];
    float4 bias1 = *(const float4*)&outb[64 + tn * 4];
#pragma unroll
    for (int i = 0; i < 4; i++) {
        size_t n = (size_t)n0 + tm * 4 + i;
        size_t rb = ((size_t)b * NPIX + n) * DIMC;
        float4 r0, r1;
        r0.x = acc[i][0] + bias0.x; r0.y = acc[i][1] + bias0.y;
        r0.z = acc[i][2] + bias0.z; r0.w = acc[i][3] + bias0.w;
        r1.x = acc[i][4] + bias1.x; r1.y = acc[i][5] + bias1.y;
        r1.z = acc[i][6] + bias1.z; r1.w = acc[i][7] + bias1.w;
        *(float4*)&out[rb + tn * 4] = r0;
        *(float4*)&out[rb + 64 + tn * 4] = r1;
    }
}

// ---------------------------------------------------------------------------
extern "C" void kernel_launch(void* const* d_in, const int* in_sizes, int n_in,
                              void* d_out, int out_size, void* d_ws, size_t ws_size,
                              hipStream_t stream)
{
    (void)in_sizes; (void)n_in; (void)out_size;
    const float* x    = (const float*)d_in[0];
    const float* wfx  = (const float*)d_in[1];
    const float* bfx  = (const float*)d_in[2];
    const float* wx   = (const float*)d_in[3];
    const float* bx   = (const float*)d_in[4];
    const float* slw  = (const float*)d_in[5];
    const float* slb  = (const float*)d_in[6];
    const float* temp = (const float*)d_in[7];
    const float* wq   = (const float*)d_in[8];
    const float* wk   = (const float*)d_in[9];
    const float* wv   = (const float*)d_in[10];
    const float* outw = (const float*)d_in[11];
    const float* outb = (const float*)d_in[12];
    float* out = (float*)d_out;
    float* W = (float*)d_ws;

    // workspace layout (float offsets)
    u16*   wcatT = (u16*)W;               // 589,824 u16
    u16*   wfxT  = (u16*)(W + 294912);    // 589,824 u16
    float* bcatL = W + 589824;            //       512
    float* zeros = W + 590336;            //        64   (zeroed; gload halo src)
    float* norm  = W + 590400;            //     4,096   (zeroed)
    float* straw = W + 594496;            //   262,144   (zeroed, contiguous)
    float* m1    = W + 856640;            //   524,288
    u16*   xbf   = (u16*)(W + 1380928);   // 16,777,216 u16 = 32 MiB (pre-swz bf16 x)
    u16*   swbT  = (u16*)(W + 9769536);   // 67,108,864 u16 = 128 MiB, [bh][g][n]
    const size_t need = 9769536ull * 4 + 67108864ull * 2;   // 173,295,872 B
    if (ws_size < need) return;

    hipMemsetAsync(zeros, 0, (64 + 4096 + 262144) * sizeof(float), stream);

    k_xbf<<<dim3(8192), 256, 0, stream>>>(x, xbf);
    k_build_w<<<dim3(1152), 256, 0, stream>>>(wx, wfx, slw, temp, wcatT, wfxT);
    k_build_b<<<dim3(1), 512, 0, stream>>>(bx, slw, slb, temp, bcatL);
    k_conv2<<<dim3(8192), 256, 0, stream>>>(xbf, wcatT, wfxT, bcatL, bfx,
                                            (const u16*)zeros, swbT, straw, norm);
    k_attn<<<dim3(64), 256, 0, stream>>>(straw, norm, wq, wk, wv, outw, m1);
    k_final<<<dim3(8, 256), 256, 0, stream>>>(swbT, m1, outb, out);
}